// Round 9
// baseline (1139.399 us; speedup 1.0000x reference)
//
#include <hip/hip_runtime.h>
#include <stdint.h>
#include <math.h>

// ---------------------------------------------------------------------------
// RSNN forward, MI355X. EXACT integer hidden GEMM (absmax 0.0156): 27-bit
// fixed-point weights -> 3 signed base-256 i8 digit planes, binary
// activations, i32 MFMA, exact int64 recombination, single fp32 round,
// fp32 program-order decay.
// Round-19: 1024-thread blocks for 4 waves/SIMD (double TLP) + spill-free
// K-loop. 256 blocks x 1024 threads, 1 block/CU (LDS-forced). Wave k ->
// fch=k>>3 (16 h-col half), kq=k&7 (K-eighth, 6 slabs). Live set:
// acc[4][3]=48 + A-dbuf 32 + B-dbuf 24 ~= 104 < 128 VGPR -> REAL double
// buffer (r17's 176-live set was silently serialized at 128). B read once
// (288 KB/CU); A twin-read is same-CU L1 hit, not extra L2 traffic.
// Merge: two rounds sharing the 96 KB red buffer -- fch0 dumps, waves 8-15
// merge fc0 (8-way epilogue: fr_e=mw&3, jj-pair=mw>>2, Hm float2); swap.
// 4 barriers/step. Integer merge reorder = exact; fp32 path untouched.
// ---------------------------------------------------------------------------

#define B_   256
#define T_   50
#define I_   1024
#define H_   2048
#define O_   20
#define XIN_T  262144    // input bytes per t: 4 bg * 16 kx * 4096
#define XS_BUF 524288    // one spike buffer: 4 bg * 32 kx * 4096
#define WNT 294912       // weight bytes per nt (32 cols): 3 * 48 * 2048
#define WPL 98304        // bytes per plane within an nt

typedef __attribute__((ext_vector_type(4))) int intx4;
typedef long long ll_t;

// ---------------------------------------------------------------------------
// Weight prep: digit p of W(n,kk) -> [nt 64][p 3][kx 48][row 32][64B]
// ---------------------------------------------------------------------------
__device__ __forceinline__ int digit_of(float v, int p) {
  int W = (int)rintf(v * 134217728.0f);   // exact: |W| <= 2^22
  int c0 = ((W + 128) & 255) - 128;
  int W1 = (W - c0) >> 8;
  int c1 = ((W1 + 128) & 255) - 128;
  int W2 = (W1 - c1) >> 8;
  return (p == 0) ? c0 : (p == 1) ? c1 : W2;
}

__global__ void prep_w(const float* __restrict__ w_ih,
                       const float* __restrict__ w_hh,
                       int8_t* __restrict__ Wtl) {
  int blk = blockIdx.x;
  int n = blk / 9, kg = blk % 9;
  int k9 = (kg * 256 + (int)threadIdx.x) * 4;   // [0, 9216)
  int p = k9 / 3072, kk = k9 % 3072;
  const float* src = (kk < 1024) ? (w_ih + n * I_ + kk)
                                 : (w_hh + n * H_ + (kk - 1024));
  float4 v = *(const float4*)src;
  int d0 = digit_of(v.x, p) & 255;
  int d1 = digit_of(v.y, p) & 255;
  int d2 = digit_of(v.z, p) & 255;
  int d3 = digit_of(v.w, p) & 255;
  int packed = d0 | (d1 << 8) | (d2 << 16) | (d3 << 24);
  size_t off = (size_t)(n >> 5) * WNT + (size_t)p * WPL + (kk >> 6) * 2048 +
               (n & 31) * 64 + (kk & 63);
  *(int*)(Wtl + off) = packed;
}

// ---------------------------------------------------------------------------
// Init: pack input for ALL t, zero spike buf0 + Hm + o-state, tables.
// ---------------------------------------------------------------------------
__global__ void init_k(int8_t* __restrict__ Xin, int8_t* __restrict__ Xs,
                       float* __restrict__ Hm, const float* __restrict__ input,
                       const float* __restrict__ tau_h,
                       const float* __restrict__ tau_o,
                       float* __restrict__ AlphaH, float* __restrict__ AlphaO,
                       const float* __restrict__ w_ho, double* __restrict__ WhoD,
                       float* __restrict__ Om, float* __restrict__ Osp,
                       float* __restrict__ Osu, float* __restrict__ Mo) {
  int id = blockIdx.x * 256 + threadIdx.x;   // [0, 65536)
  {
    int b = id >> 8, i4 = (id & 255) * 4;
    for (int t = 0; t < T_; ++t) {
      float4 v = *(const float4*)(input + ((size_t)(b * T_ + t) << 10) + i4);
      uchar4 pk;
      pk.x = v.x > 0.5f ? 1 : 0;
      pk.y = v.y > 0.5f ? 1 : 0;
      pk.z = v.z > 0.5f ? 1 : 0;
      pk.w = v.w > 0.5f ? 1 : 0;
      *(uchar4*)(Xin + (size_t)t * XIN_T + (b >> 6) * 65536 + (i4 >> 6) * 4096 +
                 (b & 63) * 64 + (i4 & 63)) = pk;
    }
  }
  *(double*)(Xs + (size_t)id * 8) = 0.0;        // zero spike buf0
  *(float4*)(Hm + (size_t)id * 8) = make_float4(0.f, 0.f, 0.f, 0.f);
  *(float4*)(Hm + (size_t)id * 8 + 4) = make_float4(0.f, 0.f, 0.f, 0.f);
  if (id < 64 * O_ * 32) {                      // WhoD [nt 64][o 20][hl 32]
    int nt = id / 640, rem = id % 640, o = rem / 32, hl = rem & 31;
    WhoD[id] = (double)w_ho[o * H_ + nt * 32 + hl];
  }
  if (id < H_) AlphaH[id] = (float)exp((double)(-1.0f / tau_h[id]));
  if (id < O_) AlphaO[id] = (float)exp((double)(-1.0f / tau_o[id]));
  if (id < B_ * O_) {
    Om[id] = 0.f; Osp[id] = 0.f; Osu[id] = 0.f; Mo[id] = 0.f;
  }
}

// ---------------------------------------------------------------------------
// Per-step kernel: 256 blocks x 1024 threads (1/CU, 4 waves/SIMD).
// Block (nt in [0,64), mg in [0,4)): 64 batch x 32 h, full K.
// Wave k in [0,16): fch=k>>3 (h-col half), kq=k&7 (K-eighth, 6 slabs).
// ---------------------------------------------------------------------------
__global__ __launch_bounds__(1024, 1) void step_k(
    const int8_t* __restrict__ Wtl, const int8_t* __restrict__ Xin,
    int8_t* __restrict__ Xs, float* __restrict__ Hm, double* __restrict__ Po,
    const double* __restrict__ WhoD, const float* __restrict__ AlphaH,
    const float* __restrict__ AlphaO, float* __restrict__ Om,
    float* __restrict__ Osp, float* __restrict__ Osu, float* __restrict__ Mo,
    int t) {
  __shared__ double WhoL[640];
  __shared__ __align__(16) int8_t red[98304];   // [slot 8][frag 12][lane 64][16B]
  __shared__ int8_t spk_lT[2048];               // [h 32][b 64]

  const int j = blockIdx.x;                     // [0,256)
  const int nt = (j & 7) * 8 + ((j >> 3) & 7);  // same nt -> same j%8 (XCD)
  const int mg = j >> 6;                        // 64-batch group [0,4)
  const int tid = threadIdx.x;
  const int l = tid & 63, k = tid >> 6;         // wave k in [0,16)
  const int r_ = l & 15, q = l >> 4;
  const int fch = k >> 3, kq = k & 7;

  if (tid < 640) WhoL[tid] = WhoD[nt * 640 + tid];

  // ---- K-loop: 6 slabs per wave, no barriers, depth-1 rotation ----
  const int arow = r_ * 64 + q * 16;
  const int8_t* Ain = Xin + (size_t)t * XIN_T + mg * 65536 + arow;
  const int8_t* Asp = Xs + (size_t)(t & 1) * XS_BUF + mg * 131072 + arow;
  int8_t* Xw = Xs + (size_t)((t + 1) & 1) * XS_BUF;
  const int8_t* Bw = Wtl + (size_t)nt * WNT + fch * 1024 + arow;
  const int u0 = kq * 6;

  intx4 acc[4][3];   // [fr][p]
#pragma unroll
  for (int fr = 0; fr < 4; ++fr)
#pragma unroll
    for (int p = 0; p < 3; ++p) acc[fr][p] = (intx4){0, 0, 0, 0};

  intx4 a[2][4], b[2][3];
  {
    const int8_t* ap = (u0 < 16) ? (Ain + u0 * 4096) : (Asp + (u0 - 16) * 4096);
#pragma unroll
    for (int fr = 0; fr < 4; ++fr) a[0][fr] = *(const intx4*)(ap + fr * 1024);
    const int8_t* bp = Bw + (size_t)u0 * 2048;
#pragma unroll
    for (int p = 0; p < 3; ++p) b[0][p] = *(const intx4*)(bp + p * WPL);
  }
#pragma unroll
  for (int i = 0; i < 6; ++i) {
    const int cur = i & 1, nxt = cur ^ 1;
    if (i < 5) {
      const int un = u0 + i + 1;
      const int8_t* ap = (un < 16) ? (Ain + un * 4096) : (Asp + (un - 16) * 4096);
#pragma unroll
      for (int fr = 0; fr < 4; ++fr) a[nxt][fr] = *(const intx4*)(ap + fr * 1024);
      const int8_t* bp = Bw + (size_t)un * 2048;
#pragma unroll
      for (int p = 0; p < 3; ++p) b[nxt][p] = *(const intx4*)(bp + p * WPL);
    }
#pragma unroll
    for (int p = 0; p < 3; ++p)
#pragma unroll
      for (int fr = 0; fr < 4; ++fr)
        acc[fr][p] = __builtin_amdgcn_mfma_i32_16x16x64_i8(
            a[cur][fr], b[cur][p], acc[fr][p], 0, 0, 0);
  }

  // ---- two-round merge over K-eighth slots, 8-way parallel epilogue ----
#define REDP(s, idx) (red + (((s) * 12 + (idx)) * 64 + l) * 16)

  // merge+epilogue body: merging wave index mw in [0,8), fc-half fcH
  auto merge_epi = [&](int mw, int fcH) {
    const int fr_e = mw & 3;                 // fragment row (16 batch)
    const int jh = mw >> 2;                  // jj-pair: 0 -> jj 0,1; 1 -> jj 2,3
    const int base = fr_e * 3;
    intx4 s0 = (intx4){0, 0, 0, 0}, s1 = s0, s2 = s0;
#pragma unroll
    for (int s = 0; s < 8; ++s) {
      s0 = s0 + *(const intx4*)REDP(s, base + 0);
      s1 = s1 + *(const intx4*)REDP(s, base + 1);
      s2 = s2 + *(const intx4*)REDP(s, base + 2);
    }
    const int h_e = nt * 32 + fcH * 16 + r_;
    const float alpha = AlphaH[h_e];
    float* hm_ptr = Hm + (size_t)j * 2048 + fcH * 1024 + mw * 128 + l * 2;
    float2 hp2 = *(float2*)hm_ptr;
    float* hp = reinterpret_cast<float*>(&hp2);
    unsigned spk01 = 0;
#pragma unroll
    for (int jj2 = 0; jj2 < 2; ++jj2) {
      const int jj = jh * 2 + jj2;
      ll_t Sv = (ll_t)s0[jj] + ((ll_t)s1[jj] << 8) + ((ll_t)s2[jj] << 16);
      float M = (float)((double)Sv * 7.450580596923828125e-9);  // * 2^-27
      float hpv = hp[jj2];
      float spf = (hpv - 0.3f) > 0.f ? 1.f : 0.f;
      float hmn = M + hpv * alpha * (1.0f - spf);   // fp32 program order
      hp[jj2] = hmn;
      unsigned spk = (hmn - 0.3f) > 0.f ? 1u : 0u;
      const int brl = fr_e * 16 + q * 4 + jj;        // batch row [0,64)
      Xw[mg * 131072 + (h_e >> 6) * 4096 + brl * 64 + (h_e & 63)] =
          (int8_t)spk;
      spk01 |= spk << (8 * jj2);
    }
    *(float2*)hm_ptr = hp2;
    *(unsigned short*)(spk_lT + (fcH * 16 + r_) * 64 + fr_e * 16 + q * 4 +
                       jh * 2) = (unsigned short)spk01;
  };

  // Round A: fch0 waves (k<8) dump; waves 8-15 merge fc-half 0
  if (k < 8) {
#pragma unroll
    for (int fr = 0; fr < 4; ++fr)
#pragma unroll
      for (int p = 0; p < 3; ++p)
        *(intx4*)REDP(k, fr * 3 + p) = acc[fr][p];
  }
  __syncthreads();
  if (k >= 8) merge_epi(k - 8, 0);
  __syncthreads();
  // Round B: fch1 waves (k>=8) dump; waves 0-7 merge fc-half 1
  if (k >= 8) {
#pragma unroll
    for (int fr = 0; fr < 4; ++fr)
#pragma unroll
      for (int p = 0; p < 3; ++p)
        *(intx4*)REDP(k - 8, fr * 3 + p) = acc[fr][p];
  }
  __syncthreads();
  if (k < 8) merge_epi(k, 1);
  __syncthreads();

  // ---- o-partials (waves 0-3) || head o-phase for t-1 (wave 15) ----
  if (tid < 256) {
    const int bl = tid >> 2, og = (tid & 3) * 5;
    const double* W0 = WhoL + og * 32;
    double a0 = 0, a1 = 0, a2 = 0, a3 = 0, a4 = 0;
#pragma unroll
    for (int hl = 0; hl < 32; ++hl) {
      double m = (double)spk_lT[hl * 64 + bl];
      a0 += m * W0[hl];
      a1 += m * W0[32 + hl];
      a2 += m * W0[64 + hl];
      a3 += m * W0[96 + hl];
      a4 += m * W0[128 + hl];
    }
    double* dst =
        Po + ((size_t)((t & 1) * 256 + mg * 64 + bl) * 64 + nt) * 20 + og;
    dst[0] = a0; dst[1] = a1; dst[2] = a2; dst[3] = a3; dst[4] = a4;
  } else if (k == 15 && t > 0) {
    // head: o-phase for step t-1, batch j. 40 lanes sum 32 nt each,
    // halves merged via one shuffle. Benign double-order change.
    const double* pb = Po + ((size_t)(((t - 1) & 1) * 256 + j) * 64) * 20;
    double s = 0.0;
    if (l < 40) {
      const int half = (l >= 20) ? 1 : 0;
      const int oo = l - half * 20;
      const double* pp = pb + (size_t)(half * 32) * 20 + oo;
#pragma unroll
      for (int n2 = 0; n2 < 32; ++n2) s += pp[n2 * 20];
    }
    double s_hi = __shfl(s, l + 20, 64);   // lanes 0..19 pull 20..39
    float m = -3.0e38f;
    if (l < O_)
      m = Om[j * O_ + l] * AlphaO[l] * (1.0f - Osp[j * O_ + l]) +
          (float)(s + s_hi);
    float mx = m;
#pragma unroll
    for (int off = 16; off > 0; off >>= 1)
      mx = fmaxf(mx, __shfl_xor(mx, off, 32));
    float eo = (l < O_) ? expf(m - mx) : 0.f;
    float se = eo;
#pragma unroll
    for (int off = 16; off > 0; off >>= 1) se += __shfl_xor(se, off, 32);
    if (l < O_) {
      float sp = (m - 0.3f) > 0.f ? 1.f : 0.f;
      Om[j * O_ + l] = m;
      Osp[j * O_ + l] = sp;
      Osu[j * O_ + l] += sp;
      Mo[j * O_ + l] += eo / se;
    }
  }
#undef REDP
}

// ---------------------------------------------------------------------------
// Final o-phase (t=49) + output write. 256 blocks x 64 threads.
// ---------------------------------------------------------------------------
__global__ void final_k(const double* __restrict__ Po,
                        const float* __restrict__ AlphaO,
                        const float* __restrict__ Om,
                        const float* __restrict__ Osp,
                        const float* __restrict__ Osu,
                        const float* __restrict__ Mo, float* __restrict__ out) {
  __shared__ float om_l[O_];
  const int j = blockIdx.x, tid = threadIdx.x;
  if (tid < O_) {
    const double* pp = Po + ((size_t)(256 + j) * 64) * 20 + tid;   // slot 1
    double s = 0.0;
#pragma unroll
    for (int n2 = 0; n2 < 64; ++n2) s += pp[n2 * 20];
    float r = (float)s;
    float m = Om[j * O_ + tid] * AlphaO[tid] * (1.0f - Osp[j * O_ + tid]) + r;
    om_l[tid] = m;
  }
  __syncthreads();
  if (tid < O_) {
    float m = om_l[tid];
    float mx = om_l[0];
#pragma unroll
    for (int o = 1; o < O_; ++o) mx = fmaxf(mx, om_l[o]);
    float se = 0.f;
#pragma unroll
    for (int o = 0; o < O_; ++o) se += expf(om_l[o] - mx);
    float sp = (m - 0.3f) > 0.f ? 1.f : 0.f;
    out[j * O_ + tid] = (Osu[j * O_ + tid] + sp) / 50.0f;
    out[B_ * O_ + j * O_ + tid] = Mo[j * O_ + tid] + expf(m - mx) / se;
  }
}

// ---------------------------------------------------------------------------
extern "C" void kernel_launch(void* const* d_in, const int* in_sizes, int n_in,
                              void* d_out, int out_size, void* d_ws, size_t ws_size,
                              hipStream_t stream) {
  const float* input = (const float*)d_in[0];
  const float* w_ih  = (const float*)d_in[1];
  const float* w_hh  = (const float*)d_in[2];
  const float* w_ho  = (const float*)d_in[3];
  const float* tau_h = (const float*)d_in[4];
  const float* tau_o = (const float*)d_in[5];

  char* ws = (char*)d_ws;
  // layout (bytes):
  // Wtl    @ 0          18,874,368
  // Xin    @ 18874368   13,107,200
  // Xs     @ 31981568    1,048,576
  // Po     @ 33030144    5,242,880   (2 x 256 x 64 x 20 doubles)
  // Hm     @ 38273024    2,097,152   ([blk 256][fcH 2][mw 8][lane 64][2] floats)
  // WhoD   @ 40370176      327,680
  // AlphaH @ 40697856        8,192
  // AlphaO @ 40706048          128
  // Om     @ 40706176       20,480  (then Osp, Osu, Mo)
  int8_t* Wtl    = (int8_t*)(ws);
  int8_t* Xin    = (int8_t*)(ws + 18874368);
  int8_t* Xs     = (int8_t*)(ws + 31981568);
  double* Po     = (double*)(ws + 33030144);
  float*  Hm     = (float*)(ws + 38273024);
  double* WhoD   = (double*)(ws + 40370176);
  float*  AlphaH = (float*)(ws + 40697856);
  float*  AlphaO = (float*)(ws + 40706048);
  float*  Om     = (float*)(ws + 40706176);
  float*  Osp    = (float*)(ws + 40726656);
  float*  Osu    = (float*)(ws + 40747136);
  float*  Mo     = (float*)(ws + 40767616);
  float*  out    = (float*)d_out;

  prep_w<<<2048 * 9, 256, 0, stream>>>(w_ih, w_hh, Wtl);
  init_k<<<256, 256, 0, stream>>>(Xin, Xs, Hm, input, tau_h, tau_o, AlphaH,
                                  AlphaO, w_ho, WhoD, Om, Osp, Osu, Mo);
  for (int t = 0; t < T_; ++t) {
    step_k<<<256, 1024, 0, stream>>>(Wtl, Xin, Xs, Hm, Po, WhoD, AlphaH,
                                     AlphaO, Om, Osp, Osu, Mo, t);
  }
  final_k<<<256, 64, 0, stream>>>(Po, AlphaO, Om, Osp, Osu, Mo, out);
}

// Round 10
// 1116.956 us; speedup vs baseline: 1.0201x; 1.0201x over previous
//
#include <hip/hip_runtime.h>
#include <stdint.h>
#include <math.h>

// ---------------------------------------------------------------------------
// RSNN forward, MI355X. EXACT integer hidden GEMM (absmax 0.0156): 27-bit
// fixed-point weights -> 3 signed base-256 i8 digit planes, binary
// activations, i32 MFMA, exact int64 recombination, single fp32 round,
// fp32 program-order decay.
// Round-20: PLANE-SPLIT waves. 256 blocks x 768 threads (1/CU, 12 waves,
// 3/SIMD -> VGPR budget ~168, not 128). Wave k -> plane p=k>>2, K-quarter
// kq=k&3 (12 slabs). Live set acc[4][2]=32 + A-dbuf 32 + B-dbuf 16 ~= 80
// -> REAL double-buffer (r17's 176-live set serialized at 128). Traffic:
// B read once/CU (288 KB, unique (p,kq) chunks); A read by 3 plane-twins
// running lockstep on the same CU -> L1 hits, no new L2 traffic. Single
// merge round (12 slots x 8 frags = 96 KB red), waves 0-7 sum 4 kq-slots
// per plane + exact i64 recombine + epilogue; head o-phase overlaps merge
// on idle wave 11. 2 barriers/step (r17 had 4). fp32 path byte-identical.
// ---------------------------------------------------------------------------

#define B_   256
#define T_   50
#define I_   1024
#define H_   2048
#define O_   20
#define XIN_T  262144    // input bytes per t: 4 bg * 16 kx * 4096
#define XS_BUF 524288    // one spike buffer: 4 bg * 32 kx * 4096
#define WNT 294912       // weight bytes per nt (32 cols): 3 * 48 * 2048
#define WPL 98304        // bytes per plane within an nt

typedef __attribute__((ext_vector_type(4))) int intx4;
typedef long long ll_t;

// ---------------------------------------------------------------------------
// Weight prep: digit p of W(n,kk) -> [nt 64][p 3][kx 48][row 32][64B]
// ---------------------------------------------------------------------------
__device__ __forceinline__ int digit_of(float v, int p) {
  int W = (int)rintf(v * 134217728.0f);   // exact: |W| <= 2^22
  int c0 = ((W + 128) & 255) - 128;
  int W1 = (W - c0) >> 8;
  int c1 = ((W1 + 128) & 255) - 128;
  int W2 = (W1 - c1) >> 8;
  return (p == 0) ? c0 : (p == 1) ? c1 : W2;
}

__global__ void prep_w(const float* __restrict__ w_ih,
                       const float* __restrict__ w_hh,
                       int8_t* __restrict__ Wtl) {
  int blk = blockIdx.x;
  int n = blk / 9, kg = blk % 9;
  int k9 = (kg * 256 + (int)threadIdx.x) * 4;   // [0, 9216)
  int p = k9 / 3072, kk = k9 % 3072;
  const float* src = (kk < 1024) ? (w_ih + n * I_ + kk)
                                 : (w_hh + n * H_ + (kk - 1024));
  float4 v = *(const float4*)src;
  int d0 = digit_of(v.x, p) & 255;
  int d1 = digit_of(v.y, p) & 255;
  int d2 = digit_of(v.z, p) & 255;
  int d3 = digit_of(v.w, p) & 255;
  int packed = d0 | (d1 << 8) | (d2 << 16) | (d3 << 24);
  size_t off = (size_t)(n >> 5) * WNT + (size_t)p * WPL + (kk >> 6) * 2048 +
               (n & 31) * 64 + (kk & 63);
  *(int*)(Wtl + off) = packed;
}

// ---------------------------------------------------------------------------
// Init: pack input for ALL t, zero spike buf0 + Hm + o-state, tables.
// ---------------------------------------------------------------------------
__global__ void init_k(int8_t* __restrict__ Xin, int8_t* __restrict__ Xs,
                       float* __restrict__ Hm, const float* __restrict__ input,
                       const float* __restrict__ tau_h,
                       const float* __restrict__ tau_o,
                       float* __restrict__ AlphaH, float* __restrict__ AlphaO,
                       const float* __restrict__ w_ho, double* __restrict__ WhoD,
                       float* __restrict__ Om, float* __restrict__ Osp,
                       float* __restrict__ Osu, float* __restrict__ Mo) {
  int id = blockIdx.x * 256 + threadIdx.x;   // [0, 65536)
  {
    int b = id >> 8, i4 = (id & 255) * 4;
    for (int t = 0; t < T_; ++t) {
      float4 v = *(const float4*)(input + ((size_t)(b * T_ + t) << 10) + i4);
      uchar4 pk;
      pk.x = v.x > 0.5f ? 1 : 0;
      pk.y = v.y > 0.5f ? 1 : 0;
      pk.z = v.z > 0.5f ? 1 : 0;
      pk.w = v.w > 0.5f ? 1 : 0;
      *(uchar4*)(Xin + (size_t)t * XIN_T + (b >> 6) * 65536 + (i4 >> 6) * 4096 +
                 (b & 63) * 64 + (i4 & 63)) = pk;
    }
  }
  *(double*)(Xs + (size_t)id * 8) = 0.0;        // zero spike buf0
  *(float4*)(Hm + (size_t)id * 8) = make_float4(0.f, 0.f, 0.f, 0.f);
  *(float4*)(Hm + (size_t)id * 8 + 4) = make_float4(0.f, 0.f, 0.f, 0.f);
  if (id < 64 * O_ * 32) {                      // WhoD [nt 64][o 20][hl 32]
    int nt = id / 640, rem = id % 640, o = rem / 32, hl = rem & 31;
    WhoD[id] = (double)w_ho[o * H_ + nt * 32 + hl];
  }
  if (id < H_) AlphaH[id] = (float)exp((double)(-1.0f / tau_h[id]));
  if (id < O_) AlphaO[id] = (float)exp((double)(-1.0f / tau_o[id]));
  if (id < B_ * O_) {
    Om[id] = 0.f; Osp[id] = 0.f; Osu[id] = 0.f; Mo[id] = 0.f;
  }
}

// ---------------------------------------------------------------------------
// Per-step kernel: 256 blocks x 768 threads (1/CU, 12 waves, 3 waves/SIMD).
// Block (nt in [0,64), mg in [0,4)): 64 batch x 32 h, full K.
// Wave k in [0,12): plane pw=k>>2, K-quarter kq=k&3 (12 slabs).
// Per wave: acc[4fr][2fc] for ONE digit plane.
// ---------------------------------------------------------------------------
__global__ __launch_bounds__(768, 1) void step_k(
    const int8_t* __restrict__ Wtl, const int8_t* __restrict__ Xin,
    int8_t* __restrict__ Xs, float* __restrict__ Hm, double* __restrict__ Po,
    const double* __restrict__ WhoD, const float* __restrict__ AlphaH,
    const float* __restrict__ AlphaO, float* __restrict__ Om,
    float* __restrict__ Osp, float* __restrict__ Osu, float* __restrict__ Mo,
    int t) {
  __shared__ double WhoL[640];
  __shared__ __align__(16) int8_t red[98304];   // [slot 12][frag 8][lane 64][16B]
  __shared__ int8_t spk_lT[2048];               // [h 32][b 64]

  const int j = blockIdx.x;                     // [0,256)
  const int nt = (j & 7) * 8 + ((j >> 3) & 7);  // same nt -> same j%8 (XCD)
  const int mg = j >> 6;                        // 64-batch group [0,4)
  const int tid = threadIdx.x;
  const int l = tid & 63, k = tid >> 6;         // wave k in [0,12)
  const int r_ = l & 15, q = l >> 4;
  const int pw = k >> 2, kq = k & 3;

  if (tid < 640) WhoL[tid] = WhoD[nt * 640 + tid];

  // ---- K-loop: 12 slabs per wave, one plane, depth-1 rotation ----
  const int arow = r_ * 64 + q * 16;
  const int8_t* Ain = Xin + (size_t)t * XIN_T + mg * 65536 + arow;
  const int8_t* Asp = Xs + (size_t)(t & 1) * XS_BUF + mg * 131072 + arow;
  int8_t* Xw = Xs + (size_t)((t + 1) & 1) * XS_BUF;
  const int8_t* Bw = Wtl + (size_t)nt * WNT + (size_t)pw * WPL + arow;
  const int u0 = kq * 12;

  intx4 acc[4][2];   // [fr][fc], single plane
#pragma unroll
  for (int fr = 0; fr < 4; ++fr)
#pragma unroll
    for (int fc = 0; fc < 2; ++fc) acc[fr][fc] = (intx4){0, 0, 0, 0};

  intx4 a[2][4], b[2][2];
  {
    const int8_t* ap = (u0 < 16) ? (Ain + u0 * 4096) : (Asp + (u0 - 16) * 4096);
#pragma unroll
    for (int fr = 0; fr < 4; ++fr) a[0][fr] = *(const intx4*)(ap + fr * 1024);
    const int8_t* bp = Bw + (size_t)u0 * 2048;
    b[0][0] = *(const intx4*)bp;
    b[0][1] = *(const intx4*)(bp + 1024);
  }
#pragma unroll
  for (int i = 0; i < 12; ++i) {
    const int cur = i & 1, nxt = cur ^ 1;
    if (i < 11) {
      const int un = u0 + i + 1;
      const int8_t* ap =
          (un < 16) ? (Ain + un * 4096) : (Asp + (un - 16) * 4096);
#pragma unroll
      for (int fr = 0; fr < 4; ++fr) a[nxt][fr] = *(const intx4*)(ap + fr * 1024);
      const int8_t* bp = Bw + (size_t)un * 2048;
      b[nxt][0] = *(const intx4*)bp;
      b[nxt][1] = *(const intx4*)(bp + 1024);
    }
#pragma unroll
    for (int fc = 0; fc < 2; ++fc)
#pragma unroll
      for (int fr = 0; fr < 4; ++fr)
        acc[fr][fc] = __builtin_amdgcn_mfma_i32_16x16x64_i8(
            a[cur][fr], b[cur][fc], acc[fr][fc], 0, 0, 0);
  }

  // ---- single-round merge: 12 slots dump; waves 0-7 merge + epilogue;
  //      wave 11 runs the t-1 head o-phase concurrently ----
#define REDP(s, idx) (red + (((s) * 8 + (idx)) * 64 + l) * 16)

#pragma unroll
  for (int fr = 0; fr < 4; ++fr)
#pragma unroll
    for (int fc = 0; fc < 2; ++fc)
      *(intx4*)REDP(k, fr * 2 + fc) = acc[fr][fc];
  __syncthreads();

  if (k < 8) {
    const int fr_e = k >> 1, fc_e = k & 1;
    const int base = fr_e * 2 + fc_e;
    intx4 s0 = (intx4){0, 0, 0, 0}, s1 = s0, s2 = s0;
#pragma unroll
    for (int w = 0; w < 4; ++w) {
      s0 = s0 + *(const intx4*)REDP(w, base);       // plane 0: slots 0-3
      s1 = s1 + *(const intx4*)REDP(4 + w, base);   // plane 1: slots 4-7
      s2 = s2 + *(const intx4*)REDP(8 + w, base);   // plane 2: slots 8-11
    }
    // ---- epilogue: exact recombine, fragment-contiguous Hm float4 ----
    const int h_e = nt * 32 + fc_e * 16 + r_;
    const float alpha = AlphaH[h_e];
    float* hm_ptr = Hm + (size_t)(j * 512 + tid) * 4;
    float4 hp4 = *(float4*)hm_ptr;
    float* hp = reinterpret_cast<float*>(&hp4);
    unsigned spkpack = 0;
#pragma unroll
    for (int jj = 0; jj < 4; ++jj) {
      ll_t Sv = (ll_t)s0[jj] + ((ll_t)s1[jj] << 8) + ((ll_t)s2[jj] << 16);
      float M = (float)((double)Sv * 7.450580596923828125e-9);  // * 2^-27
      float hpv = hp[jj];
      float spf = (hpv - 0.3f) > 0.f ? 1.f : 0.f;
      float hmn = M + hpv * alpha * (1.0f - spf);   // fp32 program order
      hp[jj] = hmn;
      unsigned spk = (hmn - 0.3f) > 0.f ? 1u : 0u;
      const int brl = fr_e * 16 + q * 4 + jj;        // batch row [0,64)
      Xw[mg * 131072 + (h_e >> 6) * 4096 + brl * 64 + (h_e & 63)] =
          (int8_t)spk;
      spkpack |= spk << (8 * jj);
    }
    *(float4*)hm_ptr = hp4;
    *(unsigned*)(spk_lT + (fc_e * 16 + r_) * 64 + fr_e * 16 + q * 4) =
        spkpack;
  } else if (k == 11 && t > 0) {
    // head: o-phase for step t-1, batch j (overlaps merge+epilogue).
    // 40 lanes sum 32 nt each, halves merged via one shuffle.
    const double* pb = Po + ((size_t)(((t - 1) & 1) * 256 + j) * 64) * 20;
    double s = 0.0;
    if (l < 40) {
      const int half = (l >= 20) ? 1 : 0;
      const int oo = l - half * 20;
      const double* pp = pb + (size_t)(half * 32) * 20 + oo;
#pragma unroll
      for (int n2 = 0; n2 < 32; ++n2) s += pp[n2 * 20];
    }
    double s_hi = __shfl(s, l + 20, 64);   // lanes 0..19 pull 20..39
    float m = -3.0e38f;
    if (l < O_)
      m = Om[j * O_ + l] * AlphaO[l] * (1.0f - Osp[j * O_ + l]) +
          (float)(s + s_hi);
    float mx = m;
#pragma unroll
    for (int off = 16; off > 0; off >>= 1)
      mx = fmaxf(mx, __shfl_xor(mx, off, 32));
    float eo = (l < O_) ? expf(m - mx) : 0.f;
    float se = eo;
#pragma unroll
    for (int off = 16; off > 0; off >>= 1) se += __shfl_xor(se, off, 32);
    if (l < O_) {
      float sp = (m - 0.3f) > 0.f ? 1.f : 0.f;
      Om[j * O_ + l] = m;
      Osp[j * O_ + l] = sp;
      Osu[j * O_ + l] += sp;
      Mo[j * O_ + l] += eo / se;
    }
  }
  __syncthreads();

  // ---- o-partials (first 256 threads): 32-h double dot -> Po ----
  if (tid < 256) {
    const int bl = tid >> 2, og = (tid & 3) * 5;
    const double* W0 = WhoL + og * 32;
    double a0 = 0, a1 = 0, a2 = 0, a3 = 0, a4 = 0;
#pragma unroll
    for (int hl = 0; hl < 32; ++hl) {
      double m = (double)spk_lT[hl * 64 + bl];
      a0 += m * W0[hl];
      a1 += m * W0[32 + hl];
      a2 += m * W0[64 + hl];
      a3 += m * W0[96 + hl];
      a4 += m * W0[128 + hl];
    }
    double* dst =
        Po + ((size_t)((t & 1) * 256 + mg * 64 + bl) * 64 + nt) * 20 + og;
    dst[0] = a0; dst[1] = a1; dst[2] = a2; dst[3] = a3; dst[4] = a4;
  }
#undef REDP
}

// ---------------------------------------------------------------------------
// Final o-phase (t=49) + output write. 256 blocks x 64 threads.
// ---------------------------------------------------------------------------
__global__ void final_k(const double* __restrict__ Po,
                        const float* __restrict__ AlphaO,
                        const float* __restrict__ Om,
                        const float* __restrict__ Osp,
                        const float* __restrict__ Osu,
                        const float* __restrict__ Mo, float* __restrict__ out) {
  __shared__ float om_l[O_];
  const int j = blockIdx.x, tid = threadIdx.x;
  if (tid < O_) {
    const double* pp = Po + ((size_t)(256 + j) * 64) * 20 + tid;   // slot 1
    double s = 0.0;
#pragma unroll
    for (int n2 = 0; n2 < 64; ++n2) s += pp[n2 * 20];
    float r = (float)s;
    float m = Om[j * O_ + tid] * AlphaO[tid] * (1.0f - Osp[j * O_ + tid]) + r;
    om_l[tid] = m;
  }
  __syncthreads();
  if (tid < O_) {
    float m = om_l[tid];
    float mx = om_l[0];
#pragma unroll
    for (int o = 1; o < O_; ++o) mx = fmaxf(mx, om_l[o]);
    float se = 0.f;
#pragma unroll
    for (int o = 0; o < O_; ++o) se += expf(om_l[o] - mx);
    float sp = (m - 0.3f) > 0.f ? 1.f : 0.f;
    out[j * O_ + tid] = (Osu[j * O_ + tid] + sp) / 50.0f;
    out[B_ * O_ + j * O_ + tid] = Mo[j * O_ + tid] + expf(m - mx) / se;
  }
}

// ---------------------------------------------------------------------------
extern "C" void kernel_launch(void* const* d_in, const int* in_sizes, int n_in,
                              void* d_out, int out_size, void* d_ws, size_t ws_size,
                              hipStream_t stream) {
  const float* input = (const float*)d_in[0];
  const float* w_ih  = (const float*)d_in[1];
  const float* w_hh  = (const float*)d_in[2];
  const float* w_ho  = (const float*)d_in[3];
  const float* tau_h = (const float*)d_in[4];
  const float* tau_o = (const float*)d_in[5];

  char* ws = (char*)d_ws;
  // layout (bytes):
  // Wtl    @ 0          18,874,368
  // Xin    @ 18874368   13,107,200
  // Xs     @ 31981568    1,048,576
  // Po     @ 33030144    5,242,880   (2 x 256 x 64 x 20 doubles)
  // Hm     @ 38273024    2,097,152   (fragment-contiguous, [blk 256][tid 512][4])
  // WhoD   @ 40370176      327,680
  // AlphaH @ 40697856        8,192
  // AlphaO @ 40706048          128
  // Om     @ 40706176       20,480  (then Osp, Osu, Mo)
  int8_t* Wtl    = (int8_t*)(ws);
  int8_t* Xin    = (int8_t*)(ws + 18874368);
  int8_t* Xs     = (int8_t*)(ws + 31981568);
  double* Po     = (double*)(ws + 33030144);
  float*  Hm     = (float*)(ws + 38273024);
  double* WhoD   = (double*)(ws + 40370176);
  float*  AlphaH = (float*)(ws + 40697856);
  float*  AlphaO = (float*)(ws + 40706048);
  float*  Om     = (float*)(ws + 40706176);
  float*  Osp    = (float*)(ws + 40726656);
  float*  Osu    = (float*)(ws + 40747136);
  float*  Mo     = (float*)(ws + 40767616);
  float*  out    = (float*)d_out;

  prep_w<<<2048 * 9, 256, 0, stream>>>(w_ih, w_hh, Wtl);
  init_k<<<256, 256, 0, stream>>>(Xin, Xs, Hm, input, tau_h, tau_o, AlphaH,
                                  AlphaO, w_ho, WhoD, Om, Osp, Osu, Mo);
  for (int t = 0; t < T_; ++t) {
    step_k<<<256, 768, 0, stream>>>(Wtl, Xin, Xs, Hm, Po, WhoD, AlphaH, AlphaO,
                                    Om, Osp, Osu, Mo, t);
  }
  final_k<<<256, 64, 0, stream>>>(Po, AlphaO, Om, Osp, Osu, Mo, out);
}

// Round 11
// 1040.875 us; speedup vs baseline: 1.0947x; 1.0731x over previous
//
#include <hip/hip_runtime.h>
#include <stdint.h>
#include <math.h>

// ---------------------------------------------------------------------------
// RSNN forward, MI355X. EXACT integer hidden GEMM (absmax 0.0156): 27-bit
// fixed-point weights -> 3 signed base-256 i8 digit planes, binary
// activations, i32 MFMA, exact int64 recombination, single fp32 round,
// fp32 program-order decay.
// Round-21: canonical LDS-staged GEMM (guide §5). 256 blocks x 512 threads.
// Insight from r10-r20: r17's acc lives in AGPRs (unified file) -> it never
// spilled; it is bound by private operand streaming (480 KB/CU/step, depth-1
// prefetch). Fix: cooperative async staging via global_load_lds (16B) into
// double-buffered LDS (2 x 40 KB = 12 stages of 4 slabs), stage-granular
// prefetch issued BEFORE compute (barrier drain lands after). Waves =
// Kparity(2) x fr-pair(2) x fc(2): per stage the matching-parity half
// computes (1 wave/SIMD always on MFMA) while the other half issues next
// stage. acc[2][3]=24 regs; single 2-way merge (24 KB red). Global tile
// layouts pre-swizzled (byte ^= ((row>>1)&3)<<4) so linear gload_lds dest +
// swizzled ds_read is bank-conflict-free (rule #21). i32 reorder exact;
// fp32 path byte-identical -> absmax unchanged.
// ---------------------------------------------------------------------------

#define B_   256
#define T_   50
#define I_   1024
#define H_   2048
#define O_   20
#define XIN_T  262144    // input bytes per t: 4 bg * 16 kx * 4096
#define XS_BUF 524288    // one spike buffer: 4 bg * 32 kx * 4096
#define WNT 294912       // weight bytes per nt (32 cols): 3 * 48 * 2048
#define WPL 98304        // bytes per plane within an nt

typedef __attribute__((ext_vector_type(4))) int intx4;
typedef long long ll_t;

#define SWZ(row, byte) ((byte) ^ ((((row) >> 1) & 3) << 4))

#define GLOAD_LDS16(g, l)                                        \
  __builtin_amdgcn_global_load_lds(                              \
      (const __attribute__((address_space(1))) void*)(g),        \
      (__attribute__((address_space(3))) void*)(l), 16, 0, 0)

// ---------------------------------------------------------------------------
// Weight prep: digit p of W(n,kk) -> [nt 64][p 3][kx 48][row 32][64B],
// bytes swizzled within each row for conflict-free ds_read after staging.
// ---------------------------------------------------------------------------
__device__ __forceinline__ int digit_of(float v, int p) {
  int W = (int)rintf(v * 134217728.0f);   // exact: |W| <= 2^22
  int c0 = ((W + 128) & 255) - 128;
  int W1 = (W - c0) >> 8;
  int c1 = ((W1 + 128) & 255) - 128;
  int W2 = (W1 - c1) >> 8;
  return (p == 0) ? c0 : (p == 1) ? c1 : W2;
}

__global__ void prep_w(const float* __restrict__ w_ih,
                       const float* __restrict__ w_hh,
                       int8_t* __restrict__ Wtl) {
  int blk = blockIdx.x;
  int n = blk / 9, kg = blk % 9;
  int k9 = (kg * 256 + (int)threadIdx.x) * 4;   // [0, 9216)
  int p = k9 / 3072, kk = k9 % 3072;
  const float* src = (kk < 1024) ? (w_ih + n * I_ + kk)
                                 : (w_hh + n * H_ + (kk - 1024));
  float4 v = *(const float4*)src;
  int d0 = digit_of(v.x, p) & 255;
  int d1 = digit_of(v.y, p) & 255;
  int d2 = digit_of(v.z, p) & 255;
  int d3 = digit_of(v.w, p) & 255;
  int packed = d0 | (d1 << 8) | (d2 << 16) | (d3 << 24);
  size_t off = (size_t)(n >> 5) * WNT + (size_t)p * WPL + (kk >> 6) * 2048 +
               (n & 31) * 64 + SWZ(n, kk & 63);
  *(int*)(Wtl + off) = packed;
}

// ---------------------------------------------------------------------------
// Init: pack input for ALL t (swizzled rows), zero spike buf0 + Hm +
// o-state, tables.
// ---------------------------------------------------------------------------
__global__ void init_k(int8_t* __restrict__ Xin, int8_t* __restrict__ Xs,
                       float* __restrict__ Hm, const float* __restrict__ input,
                       const float* __restrict__ tau_h,
                       const float* __restrict__ tau_o,
                       float* __restrict__ AlphaH, float* __restrict__ AlphaO,
                       const float* __restrict__ w_ho, double* __restrict__ WhoD,
                       float* __restrict__ Om, float* __restrict__ Osp,
                       float* __restrict__ Osu, float* __restrict__ Mo) {
  int id = blockIdx.x * 256 + threadIdx.x;   // [0, 65536)
  {
    int b = id >> 8, i4 = (id & 255) * 4;
    for (int t = 0; t < T_; ++t) {
      float4 v = *(const float4*)(input + ((size_t)(b * T_ + t) << 10) + i4);
      uchar4 pk;
      pk.x = v.x > 0.5f ? 1 : 0;
      pk.y = v.y > 0.5f ? 1 : 0;
      pk.z = v.z > 0.5f ? 1 : 0;
      pk.w = v.w > 0.5f ? 1 : 0;
      *(uchar4*)(Xin + (size_t)t * XIN_T + (b >> 6) * 65536 + (i4 >> 6) * 4096 +
                 (b & 63) * 64 + SWZ(b, i4 & 63)) = pk;
    }
  }
  *(double*)(Xs + (size_t)id * 8) = 0.0;        // zero spike buf0
  *(float4*)(Hm + (size_t)id * 8) = make_float4(0.f, 0.f, 0.f, 0.f);
  *(float4*)(Hm + (size_t)id * 8 + 4) = make_float4(0.f, 0.f, 0.f, 0.f);
  if (id < 64 * O_ * 32) {                      // WhoD [nt 64][o 20][hl 32]
    int nt = id / 640, rem = id % 640, o = rem / 32, hl = rem & 31;
    WhoD[id] = (double)w_ho[o * H_ + nt * 32 + hl];
  }
  if (id < H_) AlphaH[id] = (float)exp((double)(-1.0f / tau_h[id]));
  if (id < O_) AlphaO[id] = (float)exp((double)(-1.0f / tau_o[id]));
  if (id < B_ * O_) {
    Om[id] = 0.f; Osp[id] = 0.f; Osu[id] = 0.f; Mo[id] = 0.f;
  }
}

// ---------------------------------------------------------------------------
// Per-step kernel: 256 blocks x 512 threads (1/CU). Block (nt, mg):
// 64 batch x 32 h, full K, LDS-staged. Wave k -> kh=k>>2 (stage parity),
// quad=k&3 -> fp=quad>>1 (fr-pair), fc_e=quad&1. acc[2 fr][3 p].
// 12 stages x 4 slabs; stage s computed by waves kh==s&1 while the other
// half issues global_load_lds for stage s+1.
// ---------------------------------------------------------------------------
__global__ __launch_bounds__(512, 2) void step_k(
    const int8_t* __restrict__ Wtl, const int8_t* __restrict__ Xin,
    int8_t* __restrict__ Xs, float* __restrict__ Hm, double* __restrict__ Po,
    const double* __restrict__ WhoD, const float* __restrict__ AlphaH,
    const float* __restrict__ AlphaO, float* __restrict__ Om,
    float* __restrict__ Osp, float* __restrict__ Osu, float* __restrict__ Mo,
    int t) {
  __shared__ double WhoL[640];
  __shared__ __align__(16) int8_t stageL[2][40960];  // [A 16K][B 4x6K]
  __shared__ __align__(16) int8_t red[24576];        // [quad 4][frag 6][lane 64][16B]
  __shared__ int8_t spk_lT[2048];                    // [h 32][b 64]

  const int j = blockIdx.x;                     // [0,256)
  const int nt = (j & 7) * 8 + ((j >> 3) & 7);  // same nt -> same j%8 (XCD)
  const int mg = j >> 6;                        // 64-batch group [0,4)
  const int tid = threadIdx.x;
  const int l = tid & 63, k = tid >> 6;
  const int r_ = l & 15, q = l >> 4;
  const int kh = k >> 2, quad = k & 3;
  const int fp = quad >> 1, fc_e = quad & 1;

  for (int i = tid; i < 640; i += 512) WhoL[i] = WhoD[nt * 640 + i];

  const int8_t* AinU = Xin + (size_t)t * XIN_T + mg * 65536;
  const int8_t* AspU = Xs + (size_t)(t & 1) * XS_BUF + mg * 131072;
  const int8_t* BwU = Wtl + (size_t)nt * WNT;
  int8_t* Xw = Xs + (size_t)((t + 1) & 1) * XS_BUF;

  const int qsw = (q * 16) ^ (((r_ >> 1) & 3) << 4);   // swizzled byte offset

  // stage slabs [4s, 4s+4) into stageL[buf]: 40 chunks of 1 KB, 5 per wave
  auto stage_issue = [&](int s, int buf) {
    int8_t* base = &stageL[buf][0];
#pragma unroll
    for (int i = 0; i < 5; ++i) {
      const int c = k * 5 + i;
      if (c < 16) {                       // A: [slab 4][part 4] x 1 KB
        const int u = s * 4 + (c >> 2), part = c & 3;
        const int8_t* gsrc =
            ((u < 16) ? (AinU + u * 4096) : (AspU + (u - 16) * 4096)) +
            part * 1024 + l * 16;
        GLOAD_LDS16(gsrc, base + (c >> 2) * 4096 + part * 1024);
      } else {                            // B: d -> p=d>>3, u4=(d>>1)&3, half=d&1
        const int d = c - 16, p = d >> 3, u4 = (d >> 1) & 3, half = d & 1;
        const int8_t* gsrc = BwU + (size_t)p * WPL +
                             (size_t)(s * 4 + u4) * 2048 + half * 1024 + l * 16;
        GLOAD_LDS16(gsrc, base + 16384 + u4 * 6144 + p * 2048 + half * 1024);
      }
    }
  };

  intx4 acc[2][3];   // [fr2][p]
#pragma unroll
  for (int fr2 = 0; fr2 < 2; ++fr2)
#pragma unroll
    for (int p = 0; p < 3; ++p) acc[fr2][p] = (intx4){0, 0, 0, 0};

  stage_issue(0, 0);
  __syncthreads();   // drains vmcnt -> stage 0 resident

  for (int s = 0; s < 12; ++s) {
    if (s < 11) stage_issue(s + 1, (s + 1) & 1);
    if ((s & 1) == kh) {
      const int8_t* sb = &stageL[s & 1][0];
#pragma unroll
      for (int u4 = 0; u4 < 4; ++u4) {
        const int8_t* au = sb + u4 * 4096 + r_ * 64 + qsw;
        const int8_t* bu = sb + 16384 + u4 * 6144 + fc_e * 1024 + r_ * 64 + qsw;
        intx4 a0 = *(const intx4*)(au + (fp * 2) * 1024);
        intx4 a1 = *(const intx4*)(au + (fp * 2 + 1) * 1024);
        intx4 b0 = *(const intx4*)(bu);
        intx4 b1 = *(const intx4*)(bu + 2048);
        intx4 b2 = *(const intx4*)(bu + 4096);
        acc[0][0] = __builtin_amdgcn_mfma_i32_16x16x64_i8(a0, b0, acc[0][0], 0, 0, 0);
        acc[0][1] = __builtin_amdgcn_mfma_i32_16x16x64_i8(a0, b1, acc[0][1], 0, 0, 0);
        acc[0][2] = __builtin_amdgcn_mfma_i32_16x16x64_i8(a0, b2, acc[0][2], 0, 0, 0);
        acc[1][0] = __builtin_amdgcn_mfma_i32_16x16x64_i8(a1, b0, acc[1][0], 0, 0, 0);
        acc[1][1] = __builtin_amdgcn_mfma_i32_16x16x64_i8(a1, b1, acc[1][1], 0, 0, 0);
        acc[1][2] = __builtin_amdgcn_mfma_i32_16x16x64_i8(a1, b2, acc[1][2], 0, 0, 0);
      }
    }
    __syncthreads();
  }

  // ---- 2-way merge: kh1 dumps, kh0 adds + epilogue; head o-phase on k==7 --
#define REDP2(qd, f) (red + (((qd) * 6 + (f)) * 64 + l) * 16)
  if (kh == 1) {
#pragma unroll
    for (int fr2 = 0; fr2 < 2; ++fr2)
#pragma unroll
      for (int p = 0; p < 3; ++p)
        *(intx4*)REDP2(quad, fr2 * 3 + p) = acc[fr2][p];
  }
  __syncthreads();
  if (kh == 0) {
#pragma unroll
    for (int fr2 = 0; fr2 < 2; ++fr2)
#pragma unroll
      for (int p = 0; p < 3; ++p)
        acc[fr2][p] = acc[fr2][p] + *(const intx4*)REDP2(quad, fr2 * 3 + p);

    // ---- epilogue: exact recombine, 8 membrane cells per thread ----
    const int h_e = nt * 32 + fc_e * 16 + r_;
    const float alpha = AlphaH[h_e];
    float* hm_ptr = Hm + (size_t)(j * 256 + tid) * 8;
    float4 hpA = *(float4*)hm_ptr;
    float4 hpB = *(float4*)(hm_ptr + 4);
#pragma unroll
    for (int fr2 = 0; fr2 < 2; ++fr2) {
      const int fr = fp * 2 + fr2;
      float* hp = reinterpret_cast<float*>(fr2 ? &hpB : &hpA);
      unsigned spkpack = 0;
#pragma unroll
      for (int jj = 0; jj < 4; ++jj) {
        ll_t Sv = (ll_t)acc[fr2][0][jj] + ((ll_t)acc[fr2][1][jj] << 8) +
                  ((ll_t)acc[fr2][2][jj] << 16);
        float M = (float)((double)Sv * 7.450580596923828125e-9);  // * 2^-27
        float hpv = hp[jj];
        float spf = (hpv - 0.3f) > 0.f ? 1.f : 0.f;
        float hmn = M + hpv * alpha * (1.0f - spf);   // fp32 program order
        hp[jj] = hmn;
        unsigned spk = (hmn - 0.3f) > 0.f ? 1u : 0u;
        const int brl = fr * 16 + q * 4 + jj;          // batch row [0,64)
        Xw[mg * 131072 + (h_e >> 6) * 4096 + brl * 64 + SWZ(brl, h_e & 63)] =
            (int8_t)spk;
        spkpack |= spk << (8 * jj);
      }
      *(unsigned*)(spk_lT + (fc_e * 16 + r_) * 64 + fr * 16 + q * 4) = spkpack;
    }
    *(float4*)hm_ptr = hpA;
    *(float4*)(hm_ptr + 4) = hpB;
  } else if (k == 7 && t > 0) {
    // head: o-phase for step t-1, batch j (overlaps kh0 epilogue).
    const double* pb = Po + ((size_t)(((t - 1) & 1) * 256 + j) * 64) * 20;
    double s = 0.0;
    if (l < 40) {
      const int half = (l >= 20) ? 1 : 0;
      const int oo = l - half * 20;
      const double* pp = pb + (size_t)(half * 32) * 20 + oo;
#pragma unroll
      for (int n2 = 0; n2 < 32; ++n2) s += pp[n2 * 20];
    }
    double s_hi = __shfl(s, l + 20, 64);   // lanes 0..19 pull 20..39
    float m = -3.0e38f;
    if (l < O_)
      m = Om[j * O_ + l] * AlphaO[l] * (1.0f - Osp[j * O_ + l]) +
          (float)(s + s_hi);
    float mx = m;
#pragma unroll
    for (int off = 16; off > 0; off >>= 1)
      mx = fmaxf(mx, __shfl_xor(mx, off, 32));
    float eo = (l < O_) ? expf(m - mx) : 0.f;
    float se = eo;
#pragma unroll
    for (int off = 16; off > 0; off >>= 1) se += __shfl_xor(se, off, 32);
    if (l < O_) {
      float sp = (m - 0.3f) > 0.f ? 1.f : 0.f;
      Om[j * O_ + l] = m;
      Osp[j * O_ + l] = sp;
      Osu[j * O_ + l] += sp;
      Mo[j * O_ + l] += eo / se;
    }
  }
  __syncthreads();

  // ---- o-partials (first 256 threads): 32-h double dot -> Po ----
  if (tid < 256) {
    const int bl = tid >> 2, og = (tid & 3) * 5;
    const double* W0 = WhoL + og * 32;
    double a0 = 0, a1 = 0, a2 = 0, a3 = 0, a4 = 0;
#pragma unroll
    for (int hl = 0; hl < 32; ++hl) {
      double m = (double)spk_lT[hl * 64 + bl];
      a0 += m * W0[hl];
      a1 += m * W0[32 + hl];
      a2 += m * W0[64 + hl];
      a3 += m * W0[96 + hl];
      a4 += m * W0[128 + hl];
    }
    double* dst =
        Po + ((size_t)((t & 1) * 256 + mg * 64 + bl) * 64 + nt) * 20 + og;
    dst[0] = a0; dst[1] = a1; dst[2] = a2; dst[3] = a3; dst[4] = a4;
  }
#undef REDP2
}

// ---------------------------------------------------------------------------
// Final o-phase (t=49) + output write. 256 blocks x 64 threads.
// ---------------------------------------------------------------------------
__global__ void final_k(const double* __restrict__ Po,
                        const float* __restrict__ AlphaO,
                        const float* __restrict__ Om,
                        const float* __restrict__ Osp,
                        const float* __restrict__ Osu,
                        const float* __restrict__ Mo, float* __restrict__ out) {
  __shared__ float om_l[O_];
  const int j = blockIdx.x, tid = threadIdx.x;
  if (tid < O_) {
    const double* pp = Po + ((size_t)(256 + j) * 64) * 20 + tid;   // slot 1
    double s = 0.0;
#pragma unroll
    for (int n2 = 0; n2 < 64; ++n2) s += pp[n2 * 20];
    float r = (float)s;
    float m = Om[j * O_ + tid] * AlphaO[tid] * (1.0f - Osp[j * O_ + tid]) + r;
    om_l[tid] = m;
  }
  __syncthreads();
  if (tid < O_) {
    float m = om_l[tid];
    float mx = om_l[0];
#pragma unroll
    for (int o = 1; o < O_; ++o) mx = fmaxf(mx, om_l[o]);
    float se = 0.f;
#pragma unroll
    for (int o = 0; o < O_; ++o) se += expf(om_l[o] - mx);
    float sp = (m - 0.3f) > 0.f ? 1.f : 0.f;
    out[j * O_ + tid] = (Osu[j * O_ + tid] + sp) / 50.0f;
    out[B_ * O_ + j * O_ + tid] = Mo[j * O_ + tid] + expf(m - mx) / se;
  }
}

// ---------------------------------------------------------------------------
extern "C" void kernel_launch(void* const* d_in, const int* in_sizes, int n_in,
                              void* d_out, int out_size, void* d_ws, size_t ws_size,
                              hipStream_t stream) {
  const float* input = (const float*)d_in[0];
  const float* w_ih  = (const float*)d_in[1];
  const float* w_hh  = (const float*)d_in[2];
  const float* w_ho  = (const float*)d_in[3];
  const float* tau_h = (const float*)d_in[4];
  const float* tau_o = (const float*)d_in[5];

  char* ws = (char*)d_ws;
  // layout (bytes):
  // Wtl    @ 0          18,874,368
  // Xin    @ 18874368   13,107,200
  // Xs     @ 31981568    1,048,576
  // Po     @ 33030144    5,242,880   (2 x 256 x 64 x 20 doubles)
  // Hm     @ 38273024    2,097,152   ([blk 256][tid 256][8] floats)
  // WhoD   @ 40370176      327,680
  // AlphaH @ 40697856        8,192
  // AlphaO @ 40706048          128
  // Om     @ 40706176       20,480  (then Osp, Osu, Mo)
  int8_t* Wtl    = (int8_t*)(ws);
  int8_t* Xin    = (int8_t*)(ws + 18874368);
  int8_t* Xs     = (int8_t*)(ws + 31981568);
  double* Po     = (double*)(ws + 33030144);
  float*  Hm     = (float*)(ws + 38273024);
  double* WhoD   = (double*)(ws + 40370176);
  float*  AlphaH = (float*)(ws + 40697856);
  float*  AlphaO = (float*)(ws + 40706048);
  float*  Om     = (float*)(ws + 40706176);
  float*  Osp    = (float*)(ws + 40726656);
  float*  Osu    = (float*)(ws + 40747136);
  float*  Mo     = (float*)(ws + 40767616);
  float*  out    = (float*)d_out;

  prep_w<<<2048 * 9, 256, 0, stream>>>(w_ih, w_hh, Wtl);
  init_k<<<256, 256, 0, stream>>>(Xin, Xs, Hm, input, tau_h, tau_o, AlphaH,
                                  AlphaO, w_ho, WhoD, Om, Osp, Osu, Mo);
  for (int t = 0; t < T_; ++t) {
    step_k<<<256, 512, 0, stream>>>(Wtl, Xin, Xs, Hm, Po, WhoD, AlphaH, AlphaO,
                                    Om, Osp, Osu, Mo, t);
  }
  final_k<<<256, 64, 0, stream>>>(Po, AlphaO, Om, Osp, Osu, Mo, out);
}

// Round 12
// 890.689 us; speedup vs baseline: 1.2792x; 1.1686x over previous
//
#include <hip/hip_runtime.h>
#include <stdint.h>
#include <math.h>

// ---------------------------------------------------------------------------
// RSNN forward, MI355X. EXACT integer hidden GEMM (absmax 0.0156): 27-bit
// fixed-point weights -> 3 signed base-256 i8 digit planes, binary
// activations, i32 MFMA, exact int64 recombination, single fp32 round,
// fp32 program-order decay.
// Round-22: REVERT to r17/r18 (890.7 us, session best). Five structural
// alternatives all measured slower: r15 kb-split (1036, B panel x2),
// r16 fcg-split (972, A-dup via L2 + Hm layout regression), r19 16-wave
// (1139, A-dup + half-idle merges), r20 plane-split (1117), r21 LDS-staged
// (1041, vmcnt(0) barrier drain per stage). r17 wins because: K-eighth
// split = zero operand duplication (A 192 KB + B 288 KB per CU per step),
// accumulators live in AGPRs (unified file; never spilled despite
// VGPR_Count=128), real depth-1 dbuf, 2-round LDS merge with parallel
// epilogue, fragment-contiguous Hm float4, coalesced 40-lane head o-phase.
// Declared practical plateau for this search.
// ---------------------------------------------------------------------------

#define B_   256
#define T_   50
#define I_   1024
#define H_   2048
#define O_   20
#define XIN_T  262144    // input bytes per t: 4 bg * 16 kx * 4096
#define XS_BUF 524288    // one spike buffer: 4 bg * 32 kx * 4096
#define WNT 294912       // weight bytes per nt (32 cols): 3 * 48 * 2048
#define WPL 98304        // bytes per plane within an nt

typedef __attribute__((ext_vector_type(4))) int intx4;
typedef long long ll_t;

// ---------------------------------------------------------------------------
// Weight prep: digit p of W(n,kk) -> [nt 64][p 3][kx 48][row 32][64B]
// ---------------------------------------------------------------------------
__device__ __forceinline__ int digit_of(float v, int p) {
  int W = (int)rintf(v * 134217728.0f);   // exact: |W| <= 2^22
  int c0 = ((W + 128) & 255) - 128;
  int W1 = (W - c0) >> 8;
  int c1 = ((W1 + 128) & 255) - 128;
  int W2 = (W1 - c1) >> 8;
  return (p == 0) ? c0 : (p == 1) ? c1 : W2;
}

__global__ void prep_w(const float* __restrict__ w_ih,
                       const float* __restrict__ w_hh,
                       int8_t* __restrict__ Wtl) {
  int blk = blockIdx.x;
  int n = blk / 9, kg = blk % 9;
  int k9 = (kg * 256 + (int)threadIdx.x) * 4;   // [0, 9216)
  int p = k9 / 3072, kk = k9 % 3072;
  const float* src = (kk < 1024) ? (w_ih + n * I_ + kk)
                                 : (w_hh + n * H_ + (kk - 1024));
  float4 v = *(const float4*)src;
  int d0 = digit_of(v.x, p) & 255;
  int d1 = digit_of(v.y, p) & 255;
  int d2 = digit_of(v.z, p) & 255;
  int d3 = digit_of(v.w, p) & 255;
  int packed = d0 | (d1 << 8) | (d2 << 16) | (d3 << 24);
  size_t off = (size_t)(n >> 5) * WNT + (size_t)p * WPL + (kk >> 6) * 2048 +
               (n & 31) * 64 + (kk & 63);
  *(int*)(Wtl + off) = packed;
}

// ---------------------------------------------------------------------------
// Init: pack input for ALL t, zero spike buf0 + Hm + o-state, tables.
// ---------------------------------------------------------------------------
__global__ void init_k(int8_t* __restrict__ Xin, int8_t* __restrict__ Xs,
                       float* __restrict__ Hm, const float* __restrict__ input,
                       const float* __restrict__ tau_h,
                       const float* __restrict__ tau_o,
                       float* __restrict__ AlphaH, float* __restrict__ AlphaO,
                       const float* __restrict__ w_ho, double* __restrict__ WhoD,
                       float* __restrict__ Om, float* __restrict__ Osp,
                       float* __restrict__ Osu, float* __restrict__ Mo) {
  int id = blockIdx.x * 256 + threadIdx.x;   // [0, 65536)
  {
    int b = id >> 8, i4 = (id & 255) * 4;
    for (int t = 0; t < T_; ++t) {
      float4 v = *(const float4*)(input + ((size_t)(b * T_ + t) << 10) + i4);
      uchar4 pk;
      pk.x = v.x > 0.5f ? 1 : 0;
      pk.y = v.y > 0.5f ? 1 : 0;
      pk.z = v.z > 0.5f ? 1 : 0;
      pk.w = v.w > 0.5f ? 1 : 0;
      *(uchar4*)(Xin + (size_t)t * XIN_T + (b >> 6) * 65536 + (i4 >> 6) * 4096 +
                 (b & 63) * 64 + (i4 & 63)) = pk;
    }
  }
  *(double*)(Xs + (size_t)id * 8) = 0.0;        // zero spike buf0
  *(float4*)(Hm + (size_t)id * 8) = make_float4(0.f, 0.f, 0.f, 0.f);
  *(float4*)(Hm + (size_t)id * 8 + 4) = make_float4(0.f, 0.f, 0.f, 0.f);
  if (id < 64 * O_ * 32) {                      // WhoD [nt 64][o 20][hl 32]
    int nt = id / 640, rem = id % 640, o = rem / 32, hl = rem & 31;
    WhoD[id] = (double)w_ho[o * H_ + nt * 32 + hl];
  }
  if (id < H_) AlphaH[id] = (float)exp((double)(-1.0f / tau_h[id]));
  if (id < O_) AlphaO[id] = (float)exp((double)(-1.0f / tau_o[id]));
  if (id < B_ * O_) {
    Om[id] = 0.f; Osp[id] = 0.f; Osu[id] = 0.f; Mo[id] = 0.f;
  }
}

// ---------------------------------------------------------------------------
// Per-step kernel: 256 blocks x 512 threads (1/CU, 2 waves/SIMD).
// Block (nt in [0,64), mg in [0,4)): 64 batch x 32 h, full K.
// Wave k in [0,8) = K-eighth (6 slabs), 4fr x 2fc x 3p acc per wave.
// ---------------------------------------------------------------------------
__global__ __launch_bounds__(512, 2) void step_k(
    const int8_t* __restrict__ Wtl, const int8_t* __restrict__ Xin,
    int8_t* __restrict__ Xs, float* __restrict__ Hm, double* __restrict__ Po,
    const double* __restrict__ WhoD, const float* __restrict__ AlphaH,
    const float* __restrict__ AlphaO, float* __restrict__ Om,
    float* __restrict__ Osp, float* __restrict__ Osu, float* __restrict__ Mo,
    int t) {
  __shared__ double WhoL[640];
  __shared__ __align__(16) int8_t red[98304];   // [wave 8][frag 12][lane 64][16B]
  __shared__ int8_t spk_lT[2048];               // [h 32][b 64]

  const int j = blockIdx.x;                     // [0,256)
  const int nt = (j & 7) * 8 + ((j >> 3) & 7);  // same nt -> same j%8 (XCD)
  const int mg = j >> 6;                        // 64-batch group [0,4)
  const int tid = threadIdx.x;
  const int l = tid & 63, k = tid >> 6;
  const int r_ = l & 15, q = l >> 4;

  for (int i = tid; i < 640; i += 512) WhoL[i] = WhoD[nt * 640 + i];

  // fixed per-thread epilogue coordinates (wave role is static; w_e == k)
  const int fr_e = (k < 4) ? (k >> 1) : (2 + ((k - 4) >> 1));
  const int fc_e = k & 1;
  const int h_e = nt * 32 + fc_e * 16 + r_;

  // ---- K-loop: 6 slabs per wave, no barriers, depth-1 rotation ----
  const int arow = r_ * 64 + q * 16;
  const int8_t* Ain = Xin + (size_t)t * XIN_T + mg * 65536 + arow;
  const int8_t* Asp = Xs + (size_t)(t & 1) * XS_BUF + mg * 131072 + arow;
  int8_t* Xw = Xs + (size_t)((t + 1) & 1) * XS_BUF;
  const int8_t* Bw = Wtl + (size_t)nt * WNT + arow;
  const int u0 = k * 6;

  intx4 acc[4][2][3];   // [fr][fc][p]
#pragma unroll
  for (int fr = 0; fr < 4; ++fr)
#pragma unroll
    for (int fc = 0; fc < 2; ++fc)
#pragma unroll
      for (int p = 0; p < 3; ++p) acc[fr][fc][p] = (intx4){0, 0, 0, 0};

  intx4 a[2][4], b[2][2][3];
  {
    const int8_t* ap = (u0 < 16) ? (Ain + u0 * 4096) : (Asp + (u0 - 16) * 4096);
#pragma unroll
    for (int fr = 0; fr < 4; ++fr) a[0][fr] = *(const intx4*)(ap + fr * 1024);
    const int8_t* bp = Bw + u0 * 2048;
#pragma unroll
    for (int p = 0; p < 3; ++p)
#pragma unroll
      for (int fc = 0; fc < 2; ++fc)
        b[0][fc][p] = *(const intx4*)(bp + p * WPL + fc * 1024);
  }
#pragma unroll
  for (int i = 0; i < 6; ++i) {
    const int cur = i & 1, nxt = cur ^ 1;
    if (i < 5) {
      const int un = u0 + i + 1;
      const int8_t* ap = (un < 16) ? (Ain + un * 4096) : (Asp + (un - 16) * 4096);
#pragma unroll
      for (int fr = 0; fr < 4; ++fr) a[nxt][fr] = *(const intx4*)(ap + fr * 1024);
      const int8_t* bp = Bw + un * 2048;
#pragma unroll
      for (int p = 0; p < 3; ++p)
#pragma unroll
        for (int fc = 0; fc < 2; ++fc)
          b[nxt][fc][p] = *(const intx4*)(bp + p * WPL + fc * 1024);
    }
#pragma unroll
    for (int fr = 0; fr < 4; ++fr)
#pragma unroll
      for (int fc = 0; fc < 2; ++fc)
#pragma unroll
        for (int p = 0; p < 3; ++p)
          acc[fr][fc][p] = __builtin_amdgcn_mfma_i32_16x16x64_i8(
              a[cur][fr], b[cur][fc][p], acc[fr][fc][p], 0, 0, 0);
  }

  // ---- exact K-eighth merge: two all-to-all LDS rounds, parallel epilogue --
#define REDP(w, idx) (red + (((w) * 12 + (idx)) * 64 + l) * 16)

  // fragment-contiguous membrane: thread's 4 cells = float4 at (j*512+tid)
  float* hm_ptr = Hm + (size_t)(j * 512 + tid) * 4;

  auto epilogue = [&](intx4 s0, intx4 s1, intx4 s2) {
    const float alpha = AlphaH[h_e];
    float4 hp4 = *(float4*)hm_ptr;
    float* hp = reinterpret_cast<float*>(&hp4);
    unsigned spkpack = 0;
#pragma unroll
    for (int jj = 0; jj < 4; ++jj) {
      ll_t Sv = (ll_t)s0[jj] + ((ll_t)s1[jj] << 8) + ((ll_t)s2[jj] << 16);
      float M = (float)((double)Sv * 7.450580596923828125e-9);  // * 2^-27
      float hpv = hp[jj];
      float spf = (hpv - 0.3f) > 0.f ? 1.f : 0.f;
      float hmn = M + hpv * alpha * (1.0f - spf);   // fp32 program order
      hp[jj] = hmn;
      unsigned spk = (hmn - 0.3f) > 0.f ? 1u : 0u;
      const int brl = fr_e * 16 + q * 4 + jj;        // batch row [0,64)
      Xw[mg * 131072 + (h_e >> 6) * 4096 + brl * 64 + (h_e & 63)] =
          (int8_t)spk;
      spkpack |= spk << (8 * jj);
    }
    *(float4*)hm_ptr = hp4;
    *(unsigned*)(spk_lT + (fc_e * 16 + r_) * 64 + fr_e * 16 + q * 4) =
        spkpack;
  };

  // ---- Round A: fragments fr 0..1 -> waves 0..3 merge + epilogue ----
#pragma unroll
  for (int fr = 0; fr < 2; ++fr)
#pragma unroll
    for (int fc = 0; fc < 2; ++fc)
#pragma unroll
      for (int p = 0; p < 3; ++p)
        *(intx4*)REDP(k, (fr * 2 + fc) * 3 + p) = acc[fr][fc][p];
  __syncthreads();
  if (k < 4) {
    const int base = (fr_e * 2 + fc_e) * 3;
    intx4 s0 = (intx4){0, 0, 0, 0}, s1 = s0, s2 = s0;
#pragma unroll
    for (int w = 0; w < 8; ++w) {
      s0 = s0 + *(const intx4*)REDP(w, base + 0);
      s1 = s1 + *(const intx4*)REDP(w, base + 1);
      s2 = s2 + *(const intx4*)REDP(w, base + 2);
    }
    epilogue(s0, s1, s2);
  }
  __syncthreads();
  // ---- Round B: fragments fr 2..3 -> waves 4..7 merge + epilogue ----
#pragma unroll
  for (int fr = 0; fr < 2; ++fr)
#pragma unroll
    for (int fc = 0; fc < 2; ++fc)
#pragma unroll
      for (int p = 0; p < 3; ++p)
        *(intx4*)REDP(k, (fr * 2 + fc) * 3 + p) = acc[2 + fr][fc][p];
  __syncthreads();
  if (k >= 4) {
    const int base = ((fr_e - 2) * 2 + fc_e) * 3;
    intx4 s0 = (intx4){0, 0, 0, 0}, s1 = s0, s2 = s0;
#pragma unroll
    for (int w = 0; w < 8; ++w) {
      s0 = s0 + *(const intx4*)REDP(w, base + 0);
      s1 = s1 + *(const intx4*)REDP(w, base + 1);
      s2 = s2 + *(const intx4*)REDP(w, base + 2);
    }
    epilogue(s0, s1, s2);
  }
  __syncthreads();

  // ---- o-partials (waves 0-3) || head o-phase for t-1 (wave 7) ----
  if (tid < 256) {
    const int bl = tid >> 2, og = (tid & 3) * 5;
    const double* W0 = WhoL + og * 32;
    double a0 = 0, a1 = 0, a2 = 0, a3 = 0, a4 = 0;
#pragma unroll
    for (int hl = 0; hl < 32; ++hl) {
      double m = (double)spk_lT[hl * 64 + bl];
      a0 += m * W0[hl];
      a1 += m * W0[32 + hl];
      a2 += m * W0[64 + hl];
      a3 += m * W0[96 + hl];
      a4 += m * W0[128 + hl];
    }
    double* dst =
        Po + ((size_t)((t & 1) * 256 + mg * 64 + bl) * 64 + nt) * 20 + og;
    dst[0] = a0; dst[1] = a1; dst[2] = a2; dst[3] = a3; dst[4] = a4;
  } else if (k == 7 && t > 0) {
    // head: o-phase for step t-1, batch j. 40 lanes sum 32 nt each
    // (coalesced ~4 lines/load vs 20-lane stride-160B), halves merged
    // via one shuffle. Benign double-order change.
    const double* pb = Po + ((size_t)(((t - 1) & 1) * 256 + j) * 64) * 20;
    double s = 0.0;
    if (l < 40) {
      const int half = (l >= 20) ? 1 : 0;
      const int oo = l - half * 20;
      const double* pp = pb + (size_t)(half * 32) * 20 + oo;
#pragma unroll
      for (int n2 = 0; n2 < 32; ++n2) s += pp[n2 * 20];
    }
    double s_hi = __shfl(s, l + 20, 64);   // lanes 0..19 pull 20..39
    float m = -3.0e38f;
    if (l < O_)
      m = Om[j * O_ + l] * AlphaO[l] * (1.0f - Osp[j * O_ + l]) +
          (float)(s + s_hi);
    float mx = m;
#pragma unroll
    for (int off = 16; off > 0; off >>= 1)
      mx = fmaxf(mx, __shfl_xor(mx, off, 32));
    float eo = (l < O_) ? expf(m - mx) : 0.f;
    float se = eo;
#pragma unroll
    for (int off = 16; off > 0; off >>= 1) se += __shfl_xor(se, off, 32);
    if (l < O_) {
      float sp = (m - 0.3f) > 0.f ? 1.f : 0.f;
      Om[j * O_ + l] = m;
      Osp[j * O_ + l] = sp;
      Osu[j * O_ + l] += sp;
      Mo[j * O_ + l] += eo / se;
    }
  }
#undef REDP
}

// ---------------------------------------------------------------------------
// Final o-phase (t=49) + output write. 256 blocks x 64 threads.
// ---------------------------------------------------------------------------
__global__ void final_k(const double* __restrict__ Po,
                        const float* __restrict__ AlphaO,
                        const float* __restrict__ Om,
                        const float* __restrict__ Osp,
                        const float* __restrict__ Osu,
                        const float* __restrict__ Mo, float* __restrict__ out) {
  __shared__ float om_l[O_];
  const int j = blockIdx.x, tid = threadIdx.x;
  if (tid < O_) {
    const double* pp = Po + ((size_t)(256 + j) * 64) * 20 + tid;   // slot 1
    double s = 0.0;
#pragma unroll
    for (int n2 = 0; n2 < 64; ++n2) s += pp[n2 * 20];
    float r = (float)s;
    float m = Om[j * O_ + tid] * AlphaO[tid] * (1.0f - Osp[j * O_ + tid]) + r;
    om_l[tid] = m;
  }
  __syncthreads();
  if (tid < O_) {
    float m = om_l[tid];
    float mx = om_l[0];
#pragma unroll
    for (int o = 1; o < O_; ++o) mx = fmaxf(mx, om_l[o]);
    float se = 0.f;
#pragma unroll
    for (int o = 0; o < O_; ++o) se += expf(om_l[o] - mx);
    float sp = (m - 0.3f) > 0.f ? 1.f : 0.f;
    out[j * O_ + tid] = (Osu[j * O_ + tid] + sp) / 50.0f;
    out[B_ * O_ + j * O_ + tid] = Mo[j * O_ + tid] + expf(m - mx) / se;
  }
}

// ---------------------------------------------------------------------------
extern "C" void kernel_launch(void* const* d_in, const int* in_sizes, int n_in,
                              void* d_out, int out_size, void* d_ws, size_t ws_size,
                              hipStream_t stream) {
  const float* input = (const float*)d_in[0];
  const float* w_ih  = (const float*)d_in[1];
  const float* w_hh  = (const float*)d_in[2];
  const float* w_ho  = (const float*)d_in[3];
  const float* tau_h = (const float*)d_in[4];
  const float* tau_o = (const float*)d_in[5];

  char* ws = (char*)d_ws;
  // layout (bytes):
  // Wtl    @ 0          18,874,368
  // Xin    @ 18874368   13,107,200
  // Xs     @ 31981568    1,048,576
  // Po     @ 33030144    5,242,880   (2 x 256 x 64 x 20 doubles)
  // Hm     @ 38273024    2,097,152   (fragment-contiguous, [blk 256][tid 512][4])
  // WhoD   @ 40370176      327,680
  // AlphaH @ 40697856        8,192
  // AlphaO @ 40706048          128
  // Om     @ 40706176       20,480  (then Osp, Osu, Mo)
  int8_t* Wtl    = (int8_t*)(ws);
  int8_t* Xin    = (int8_t*)(ws + 18874368);
  int8_t* Xs     = (int8_t*)(ws + 31981568);
  double* Po     = (double*)(ws + 33030144);
  float*  Hm     = (float*)(ws + 38273024);
  double* WhoD   = (double*)(ws + 40370176);
  float*  AlphaH = (float*)(ws + 40697856);
  float*  AlphaO = (float*)(ws + 40706048);
  float*  Om     = (float*)(ws + 40706176);
  float*  Osp    = (float*)(ws + 40726656);
  float*  Osu    = (float*)(ws + 40747136);
  float*  Mo     = (float*)(ws + 40767616);
  float*  out    = (float*)d_out;

  prep_w<<<2048 * 9, 256, 0, stream>>>(w_ih, w_hh, Wtl);
  init_k<<<256, 256, 0, stream>>>(Xin, Xs, Hm, input, tau_h, tau_o, AlphaH,
                                  AlphaO, w_ho, WhoD, Om, Osp, Osu, Mo);
  for (int t = 0; t < T_; ++t) {
    step_k<<<256, 512, 0, stream>>>(Wtl, Xin, Xs, Hm, Po, WhoD, AlphaH, AlphaO,
                                    Om, Osp, Osu, Mo, t);
  }
  final_k<<<256, 64, 0, stream>>>(Po, AlphaO, Om, Osp, Osu, Mo, out);
}